// Round 17
// baseline (170.277 us; speedup 1.0000x reference)
//
#include <hip/hip_runtime.h>

// SemanticConditioner: out = canvas + (embeddings @ W^T + residuals)[region_ids]
// B=4, N=65536, D=256, E=1536, R=512  (all fp32)

#define B_DIM 4
#define N_DIM 65536
#define D_DIM 256
#define E_DIM 1536
#define R_DIM 512
#define RPB   8     // embedding rows per block (cond GEMM)
#define KS    8     // K-splits (cond GEMM)
#define KSUB  (E_DIM / KS)      // 192
#define KSUB4 (KSUB / 4)        // 48
#define NGRP  (R_DIM / RPB)     // 64 r-groups

typedef float f32x4 __attribute__((ext_vector_type(4)));

// ---------------------------------------------------------------------------
// Kernel 1 (fused split-K GEMM + last-block reduce):
// Phase A (all 512 blocks): part[ks][r][d] = sum_{e in ks-chunk} emb[r][e]*W[d][e]
//   (W read directly: thread d reads its own contiguous W-row chunk as float4.)
// Then __threadfence() + atomicInc(counter[r-group]); the 8th arriver
// re-reads the 8 partials in FIXED ks order (bitwise-deterministic) + res
// and writes cond. rocPRIM-style decoupled pattern; device-scope atomics
// provide the cross-XCD ordering. Counters zeroed per call by memset.
// grid (NGRP, KS) = (64, 8) = 512 blocks, 256 threads.
// ---------------------------------------------------------------------------
__global__ __launch_bounds__(256) void k_cond_fused(const float* __restrict__ emb,
                                                    const float* __restrict__ W,
                                                    const float* __restrict__ res,
                                                    float* __restrict__ part,
                                                    float* __restrict__ cond,
                                                    int* __restrict__ counters) {
    __shared__ f32x4 embs[RPB][KSUB4];  // 6 KB
    __shared__ int lastFlag;
    const int grp = blockIdx.x;         // r-group 0..63
    const int r0  = grp * RPB;
    const int ks  = blockIdx.y;
    const int d   = threadIdx.x;

    const f32x4* eg = reinterpret_cast<const f32x4*>(emb);
    for (int f = d; f < RPB * KSUB4; f += 256) {
        const int rr = f / KSUB4, gg = f % KSUB4;
        embs[rr][gg] = eg[(size_t)(r0 + rr) * (E_DIM / 4) + ks * KSUB4 + gg];
    }
    __syncthreads();

    float a0 = 0.f, a1 = 0.f, a2 = 0.f, a3 = 0.f;
    float a4 = 0.f, a5 = 0.f, a6 = 0.f, a7 = 0.f;
    const f32x4* wrow =
        reinterpret_cast<const f32x4*>(W + (size_t)d * E_DIM + ks * KSUB);
#pragma unroll 4
    for (int g = 0; g < KSUB4; ++g) {
        const f32x4 w = wrow[g];
        const float w0 = w.x, w1 = w.y, w2 = w.z, w3 = w.w;
        { const f32x4 v = embs[0][g]; a0 += v.x*w0 + v.y*w1 + v.z*w2 + v.w*w3; }
        { const f32x4 v = embs[1][g]; a1 += v.x*w0 + v.y*w1 + v.z*w2 + v.w*w3; }
        { const f32x4 v = embs[2][g]; a2 += v.x*w0 + v.y*w1 + v.z*w2 + v.w*w3; }
        { const f32x4 v = embs[3][g]; a3 += v.x*w0 + v.y*w1 + v.z*w2 + v.w*w3; }
        { const f32x4 v = embs[4][g]; a4 += v.x*w0 + v.y*w1 + v.z*w2 + v.w*w3; }
        { const f32x4 v = embs[5][g]; a5 += v.x*w0 + v.y*w1 + v.z*w2 + v.w*w3; }
        { const f32x4 v = embs[6][g]; a6 += v.x*w0 + v.y*w1 + v.z*w2 + v.w*w3; }
        { const f32x4 v = embs[7][g]; a7 += v.x*w0 + v.y*w1 + v.z*w2 + v.w*w3; }
    }
    float* p = part + ((size_t)ks * R_DIM + r0) * D_DIM + d;
    p[0 * D_DIM] = a0;
    p[1 * D_DIM] = a1;
    p[2 * D_DIM] = a2;
    p[3 * D_DIM] = a3;
    p[4 * D_DIM] = a4;
    p[5 * D_DIM] = a5;
    p[6 * D_DIM] = a6;
    p[7 * D_DIM] = a7;

    // make partials device-visible, then count arrivals for this r-group
    __threadfence();
    if (d == 0) {
        const int old = __hip_atomic_fetch_add(&counters[grp], 1,
                                               __ATOMIC_ACQ_REL,
                                               __HIP_MEMORY_SCOPE_AGENT);
        lastFlag = (old == KS - 1);
    }
    __syncthreads();
    if (!lastFlag) return;

    __threadfence();  // acquire side: order subsequent part reads
    // last arriver reduces the whole r-group: 8 rows x 256 d
    const size_t stride = (size_t)R_DIM * D_DIM;
#pragma unroll
    for (int row = 0; row < RPB; ++row) {
        const size_t idx = (size_t)(r0 + row) * D_DIM + d;
        float s = res[idx];
#pragma unroll
        for (int k = 0; k < KS; ++k)   // fixed order -> deterministic sum
            s += part[idx + k * stride];
        cond[idx] = s;
    }
}

// ---------------------------------------------------------------------------
// Kernel 2: out = canvas + cond[region_ids]   — EXACT R16 winner (best: 110.4)
// NT canvas loads (no-allocate: cede L3 to out) + plain cached stores
// (out allocates; 256 MB fits the 256 MB memory-side L3, absorbing rewrites).
// Scalar rid path (readfirstlane -> s_load, off the vmcnt queue).
// 16384 blocks (measured optimum), b-fused 4 rows per thread.
// ---------------------------------------------------------------------------
__global__ __launch_bounds__(256) void k_add(const f32x4* __restrict__ canvas,
                                             const int* __restrict__ rid,
                                             const f32x4* __restrict__ cond,
                                             f32x4* __restrict__ out) {
    const int bstep = N_DIM * (D_DIM / 4);                  // 4,194,304 float4
    const int i = blockIdx.x * blockDim.x + threadIdx.x;    // n*64 + d4
    const int n = __builtin_amdgcn_readfirstlane(i >> 6);
    const int r = rid[n];               // s_load: issues first, off vmcnt
    const f32x4 c0 = __builtin_nontemporal_load(&canvas[i]);
    const f32x4 c1 = __builtin_nontemporal_load(&canvas[i + bstep]);
    const f32x4 c2 = __builtin_nontemporal_load(&canvas[i + 2 * bstep]);
    const f32x4 c3 = __builtin_nontemporal_load(&canvas[i + 3 * bstep]);
    const int d4 = i & 63;
    const f32x4 a = cond[r * (D_DIM / 4) + d4];  // SGPR base + lane offset, L2
    out[i]             = c0 + a;
    out[i + bstep]     = c1 + a;
    out[i + 2 * bstep] = c2 + a;
    out[i + 3 * bstep] = c3 + a;
}

// ---------------------------------------------------------------------------
extern "C" void kernel_launch(void* const* d_in, const int* in_sizes, int n_in,
                              void* d_out, int out_size, void* d_ws, size_t ws_size,
                              hipStream_t stream) {
    const float* canvas = (const float*)d_in[0];  // [B,N,D]
    const float* emb    = (const float*)d_in[1];  // [R,E]
    const float* W      = (const float*)d_in[2];  // [D,E]
    const float* res    = (const float*)d_in[3];  // [R,D]
    const int*   rid    = (const int*)d_in[4];    // [N]

    // ws layout: part (KS*R*D fp32 = 4 MB) | cond (R*D fp32 = 0.5 MB) | counters
    float* part = (float*)d_ws;
    float* cond = part + (size_t)KS * R_DIM * D_DIM;
    int*   counters = (int*)(cond + (size_t)R_DIM * D_DIM);

    // zero the 64 arrival counters (stream-ordered, graph-capturable)
    hipMemsetAsync(counters, 0, NGRP * sizeof(int), stream);

    dim3 cgrid(NGRP, KS);
    k_cond_fused<<<cgrid, 256, 0, stream>>>(emb, W, res, part, cond, counters);
    k_add<<<16384, 256, 0, stream>>>((const f32x4*)canvas, rid,
                                     (const f32x4*)cond, (f32x4*)d_out);
}

// Round 18
// 110.975 us; speedup vs baseline: 1.5344x; 1.5344x over previous
//
#include <hip/hip_runtime.h>

// SemanticConditioner: out = canvas + (embeddings @ W^T + residuals)[region_ids]
// B=4, N=65536, D=256, E=1536, R=512  (all fp32)
// REVERT to R16 winner (110.4 us): both fusion attempts (cooperative launch,
// atomic last-block + memset) cost +60-70 us in this graph-capture harness.

#define B_DIM 4
#define N_DIM 65536
#define D_DIM 256
#define E_DIM 1536
#define R_DIM 512
#define RPB   8     // embedding rows per block (cond GEMM)
#define KS    8     // K-splits (cond GEMM)
#define KSUB  (E_DIM / KS)      // 192
#define KSUB4 (KSUB / 4)        // 48

typedef float f32x4 __attribute__((ext_vector_type(4)));

// ---------------------------------------------------------------------------
// Kernel 1: partial GEMM, W read directly (thread d reads its own contiguous
// W-row chunk as float4; 75% L1 hits, active set 16 KB << 32 KB L1).
// part[ks][r][d] = sum_{e in ks-chunk} emb[r][e] * W[d][e]
// grid (R/RPB, KS) = (64, 8) = 512 blocks, 256 threads
// ---------------------------------------------------------------------------
__global__ __launch_bounds__(256) void k_cond_direct(const float* __restrict__ emb,
                                                     const float* __restrict__ W,
                                                     float* __restrict__ part) {
    __shared__ f32x4 embs[RPB][KSUB4];  // 6 KB
    const int r0 = blockIdx.x * RPB;
    const int ks = blockIdx.y;
    const int d  = threadIdx.x;

    const f32x4* eg = reinterpret_cast<const f32x4*>(emb);
    for (int f = d; f < RPB * KSUB4; f += 256) {
        const int rr = f / KSUB4, gg = f % KSUB4;
        embs[rr][gg] = eg[(size_t)(r0 + rr) * (E_DIM / 4) + ks * KSUB4 + gg];
    }
    __syncthreads();

    float a0 = 0.f, a1 = 0.f, a2 = 0.f, a3 = 0.f;
    float a4 = 0.f, a5 = 0.f, a6 = 0.f, a7 = 0.f;
    const f32x4* wrow =
        reinterpret_cast<const f32x4*>(W + (size_t)d * E_DIM + ks * KSUB);
#pragma unroll 4
    for (int g = 0; g < KSUB4; ++g) {
        const f32x4 w = wrow[g];
        const float w0 = w.x, w1 = w.y, w2 = w.z, w3 = w.w;
        { const f32x4 v = embs[0][g]; a0 += v.x*w0 + v.y*w1 + v.z*w2 + v.w*w3; }
        { const f32x4 v = embs[1][g]; a1 += v.x*w0 + v.y*w1 + v.z*w2 + v.w*w3; }
        { const f32x4 v = embs[2][g]; a2 += v.x*w0 + v.y*w1 + v.z*w2 + v.w*w3; }
        { const f32x4 v = embs[3][g]; a3 += v.x*w0 + v.y*w1 + v.z*w2 + v.w*w3; }
        { const f32x4 v = embs[4][g]; a4 += v.x*w0 + v.y*w1 + v.z*w2 + v.w*w3; }
        { const f32x4 v = embs[5][g]; a5 += v.x*w0 + v.y*w1 + v.z*w2 + v.w*w3; }
        { const f32x4 v = embs[6][g]; a6 += v.x*w0 + v.y*w1 + v.z*w2 + v.w*w3; }
        { const f32x4 v = embs[7][g]; a7 += v.x*w0 + v.y*w1 + v.z*w2 + v.w*w3; }
    }
    float* p = part + ((size_t)ks * R_DIM + r0) * D_DIM + d;
    p[0 * D_DIM] = a0;
    p[1 * D_DIM] = a1;
    p[2 * D_DIM] = a2;
    p[3 * D_DIM] = a3;
    p[4 * D_DIM] = a4;
    p[5 * D_DIM] = a5;
    p[6 * D_DIM] = a6;
    p[7 * D_DIM] = a7;
}

// ---------------------------------------------------------------------------
// Kernel 2: cond[r][d] = sum_ks part[ks][r][d] + res[r][d]
// grid R*D/256 = 512 blocks, 256 threads
// ---------------------------------------------------------------------------
__global__ __launch_bounds__(256) void k_reduce(const float* __restrict__ part,
                                                const float* __restrict__ res,
                                                float* __restrict__ cond) {
    const int i = blockIdx.x * 256 + threadIdx.x;  // r*D + d
    const size_t stride = (size_t)R_DIM * D_DIM;
    float s = res[i];
#pragma unroll
    for (int ks = 0; ks < KS; ++ks)
        s += part[i + ks * stride];
    cond[i] = s;
}

// ---------------------------------------------------------------------------
// Kernel 3: out = canvas + cond[region_ids]
// NT canvas loads (no-allocate: cede L3 to out) + plain cached stores
// (out allocates; 256 MB fits the 256 MB memory-side L3, absorbing rewrites).
// Scalar rid path (readfirstlane -> s_load, off the vmcnt queue).
// 16384 blocks (measured optimum), b-fused 4 rows per thread.
// ---------------------------------------------------------------------------
__global__ __launch_bounds__(256) void k_add(const f32x4* __restrict__ canvas,
                                             const int* __restrict__ rid,
                                             const f32x4* __restrict__ cond,
                                             f32x4* __restrict__ out) {
    const int bstep = N_DIM * (D_DIM / 4);                  // 4,194,304 float4
    const int i = blockIdx.x * blockDim.x + threadIdx.x;    // n*64 + d4
    const int n = __builtin_amdgcn_readfirstlane(i >> 6);
    const int r = rid[n];               // s_load: issues first, off vmcnt
    const f32x4 c0 = __builtin_nontemporal_load(&canvas[i]);
    const f32x4 c1 = __builtin_nontemporal_load(&canvas[i + bstep]);
    const f32x4 c2 = __builtin_nontemporal_load(&canvas[i + 2 * bstep]);
    const f32x4 c3 = __builtin_nontemporal_load(&canvas[i + 3 * bstep]);
    const int d4 = i & 63;
    const f32x4 a = cond[r * (D_DIM / 4) + d4];  // SGPR base + lane offset, L2
    out[i]             = c0 + a;
    out[i + bstep]     = c1 + a;
    out[i + 2 * bstep] = c2 + a;
    out[i + 3 * bstep] = c3 + a;
}

// ---------------------------------------------------------------------------
extern "C" void kernel_launch(void* const* d_in, const int* in_sizes, int n_in,
                              void* d_out, int out_size, void* d_ws, size_t ws_size,
                              hipStream_t stream) {
    const float* canvas = (const float*)d_in[0];  // [B,N,D]
    const float* emb    = (const float*)d_in[1];  // [R,E]
    const float* W      = (const float*)d_in[2];  // [D,E]
    const float* res    = (const float*)d_in[3];  // [R,D]
    const int*   rid    = (const int*)d_in[4];    // [N]

    // ws layout: part (KS*R*D fp32 = 4 MB) | cond (R*D fp32 = 0.5 MB)
    float* part = (float*)d_ws;
    float* cond = part + (size_t)KS * R_DIM * D_DIM;

    dim3 cgrid(R_DIM / RPB, KS);
    k_cond_direct<<<cgrid, 256, 0, stream>>>(emb, W, part);
    k_reduce<<<(R_DIM * D_DIM) / 256, 256, 0, stream>>>(part, res, cond);
    k_add<<<16384, 256, 0, stream>>>((const f32x4*)canvas, rid,
                                     (const f32x4*)cond, (f32x4*)d_out);
}